// Round 4
// baseline (257.426 us; speedup 1.0000x reference)
//
#include <hip/hip_runtime.h>
#include <cstdint>
#include <cstddef>

#define IMSIZE 4096
#define HALF 15              // LINEWIDTH//2
#define SENT (-100000)       // "no line point at this major index"
#define INT_MAXV 0x7fffffff
#define INT_MINV (-0x7fffffff - 1)

// ---------------------------------------------------------------------------
// Line parameters from the 4 input scalars. The reference's Bresenham variant
// has closed form k_i = floor((2*dY*i + dX)/(2*dX)) (validated: absmax = 0 in
// rounds 2-3), and M(i) = Mbase +/- i is exactly invertible for these
// integer-valued fp32 coordinates — so any block can reconstruct any map
// window locally from the scalars, with no global map array.
// ---------------------------------------------------------------------------
struct LineP {
    int steep, saPos, Mbase, n, Mend, mnend;
    float b0, sb;
    double twodY, twodX, ddX;
};

__device__ __forceinline__ LineP line_params(
    const float* __restrict__ x0p, const float* __restrict__ y0p,
    const float* __restrict__ x1p, const float* __restrict__ y1p)
{
    float x0 = x0p[0], y0 = y0p[0], x1 = x1p[0], y1 = y1p[0];
    float dx = fabsf(x1 - x0), dy = fabsf(y1 - y0);
    float sx = (x1 > x0) ? 1.f : -1.f;
    float sy = (y1 > y0) ? 1.f : -1.f;
    LineP P;
    P.steep = dy > dx;
    float a0 = P.steep ? y0 : x0;
    float dX = P.steep ? dy : dx;
    float dY = P.steep ? dx : dy;
    float sa = P.steep ? sy : sx;
    P.b0 = P.steep ? x0 : y0;
    P.sb = P.steep ? sx : sy;
    P.saPos = sa > 0.f;
    P.Mbase = (int)a0;
    P.n     = (int)dX;
    P.Mend  = P.steep ? (int)y1 : (int)x1;   // endpoint set last in reference
    P.mnend = P.steep ? (int)x1 : (int)y1;
    P.twodY = 2.0 * (double)dY;
    P.twodX = 2.0 * (double)dX;
    P.ddX   = (double)dX;
    return P;
}

__device__ __forceinline__ int map_at(const LineP& P, int m)
{
    if ((unsigned)m >= IMSIZE) return SENT;
    if (m == P.Mend) return P.mnend;                 // endpoint overrides
    int i = P.saPos ? (m - P.Mbase) : (P.Mbase - m);
    if (i < 0 || i >= P.n) return SENT;
    int ki = (int)floor((P.twodY * (double)i + P.ddX) / P.twodX);
    float bi = P.b0 + P.sb * (float)ki;
    return (int)bi;
}

// Build the 31-entry window around major index M in LDS; return [L,H] band
// (minor axis) or L>H if empty. Also leaves window in wmap.
__device__ __forceinline__ void band_window(
    const LineP& P, int M, int t, int* wmap, int& L, int& H)
{
    if (t < 2 * HALF + 1) wmap[t] = map_at(P, M - HALF + t);
    __syncthreads();
    int v = (t < 2 * HALF + 1) ? wmap[t] : SENT;
    int vmin = (v <= SENT / 2) ? INT_MAXV : v;
    int vmax = (v <= SENT / 2) ? INT_MINV : v;
    #pragma unroll
    for (int o = 32; o >= 1; o >>= 1) {
        vmin = min(vmin, __shfl_xor(vmin, o));
        vmax = max(vmax, __shfl_xor(vmax, o));
    }
    if (vmin == INT_MAXV) { L = 1; H = 0; }
    else { L = max(vmin - HALF, 0); H = min(vmax + HALF, IMSIZE - 1); }
}

// Integer conv weight sum at (major M, minor j) using the LDS window.
__device__ __forceinline__ int conv_w(const int* __restrict__ wmap, int j)
{
    int s = 0;
    #pragma unroll
    for (int dm = -HALF; dm <= HALF; ++dm) {
        int c = wmap[dm + HALF];            // SENT/OOB -> ad huge -> skipped
        int ad = abs(c - j);
        if (ad <= HALF) s += 16 - max(ad, (dm < 0 ? -dm : dm));
    }
    return s;
}

// ---------------------------------------------------------------------------
// K1: streaming fill, grid-stride (G11: ~2048 blocks, 24 float4/thread).
// Block 0 also zeroes the smax accumulator (stream order covers k_smax).
// ---------------------------------------------------------------------------
__global__ __launch_bounds__(256) void k_fill(float4* __restrict__ out,
                                              int* __restrict__ hdr)
{
    if (blockIdx.x == 0 && threadIdx.x == 0) hdr[1] = 0;
    const size_t N4 = (size_t)3 * IMSIZE * IMSIZE / 4;
    size_t stride = (size_t)gridDim.x * 256;
    const float4 one = make_float4(1.f, 1.f, 1.f, 1.f);
    for (size_t i = (size_t)blockIdx.x * 256 + threadIdx.x; i < N4; i += stride)
        out[i] = one;
}

// ---------------------------------------------------------------------------
// K2: per major index M, integer conv max over the band -> atomicMax smax.
// ---------------------------------------------------------------------------
__global__ __launch_bounds__(64) void k_smax(
    const float* __restrict__ x0p, const float* __restrict__ y0p,
    const float* __restrict__ x1p, const float* __restrict__ y1p,
    int* __restrict__ hdr)
{
    __shared__ int wmap[32];
    LineP P = line_params(x0p, y0p, x1p, y1p);
    int M = blockIdx.x, t = threadIdx.x;
    int L, H;
    band_window(P, M, t, wmap, L, H);

    int smax = 0;
    for (int j = L + t; j <= H; j += 64)                // width <= 61
        smax = max(smax, conv_w(wmap, j));
    #pragma unroll
    for (int o = 32; o >= 1; o >>= 1) smax = max(smax, __shfl_xor(smax, o));
    if (t == 0) atomicMax(hdr + 1, smax);
}

// ---------------------------------------------------------------------------
// K3: patch band pixels with 1 - s/smax (the 3*(.)/16 kernel factor cancels
// in min/max normalization; tmin = 0 since conv >= 0 and the band is sparse).
// ---------------------------------------------------------------------------
__global__ __launch_bounds__(64) void k_patch(
    const float* __restrict__ x0p, const float* __restrict__ y0p,
    const float* __restrict__ x1p, const float* __restrict__ y1p,
    const int* __restrict__ hdr, float* __restrict__ out)
{
    __shared__ int wmap[32];
    LineP P = line_params(x0p, y0p, x1p, y1p);
    int M = blockIdx.x, t = threadIdx.x;
    int L, H;
    band_window(P, M, t, wmap, L, H);
    if (L > H) return;

    float inv = 1.0f / (float)hdr[1];
    const size_t CH = (size_t)IMSIZE * IMSIZE;
    for (int j = L + t; j <= H; j += 64) {
        int s = conv_w(wmap, j);
        float val = 1.0f - (float)s * inv;
        int row = P.steep ? j : M;
        int col = P.steep ? M : j;
        size_t p = (size_t)row * IMSIZE + col;
        out[p]          = val;
        out[p + CH]     = val;
        out[p + 2 * CH] = val;
    }
}

// ---------------------------------------------------------------------------
extern "C" void kernel_launch(void* const* d_in, const int* in_sizes, int n_in,
                              void* d_out, int out_size, void* d_ws, size_t ws_size,
                              hipStream_t stream)
{
    const float* x0 = (const float*)d_in[0];
    const float* y0 = (const float*)d_in[1];
    const float* x1 = (const float*)d_in[2];
    const float* y1 = (const float*)d_in[3];

    int* hdr = (int*)d_ws;             // [1] = smax accumulator
    float* out = (float*)d_out;

    hipLaunchKernelGGL(k_fill,  dim3(2048),   dim3(256), 0, stream,
                       (float4*)out, hdr);
    hipLaunchKernelGGL(k_smax,  dim3(IMSIZE), dim3(64),  0, stream,
                       x0, y0, x1, y1, hdr);
    hipLaunchKernelGGL(k_patch, dim3(IMSIZE), dim3(64),  0, stream,
                       x0, y0, x1, y1, hdr, out);
}